// Round 7
// baseline (149.745 us; speedup 1.0000x reference)
//
#include <hip/hip_runtime.h>
#include <hip/hip_bf16.h>
#include <math.h>

#define NNODES 50000
#define NF 128
#define NEDGES 800000
#define ALPHA 0.2f
#define EPS 1e-16f
#define NBLK 196            // ceil(50000/256) chunks for the hierarchical scan
#define EPT 8               // edges per thread in edge passes
#define GEMM_BLOCKS 782     // ceil(50000/64)
#define CNT_BLOCKS 391      // ceil(800000/(8*256))
#define MAXDEG 128          // LDS weight-cache fast path limit (expected max deg ~35)

// bf16 RNE pack helpers
__device__ inline unsigned bf16rne(float x) {
    unsigned u = __float_as_uint(x);
    return (u + 0x7FFFu + ((u >> 16) & 1u)) >> 16;
}
__device__ inline unsigned pack2bf(float lo, float hi) {
    return bf16rne(lo) | (bf16rne(hi) << 16);
}

// ---------------------------------------------------------------------------
// K1 (fat): blocks [0, GEMM_BLOCKS): Wh_bf16 = bf16(h @ W) + fused s1/s2.
//           blocks [GEMM_BLOCKS, +CNT_BLOCKS): degree histogram + edge rank.
// GEMM mapping: wave w owns rows [rg, rg+16) x all 128 cols; lane owns 2 cols.
//   - hs reads are wave-uniform (LDS broadcast, conflict-free)
//   - W reads: 512B contiguous per wave per k-substep, 4 FMA/byte, prefetched
//   - 32KB LDS -> 5 blocks/CU so count blocks stay co-resident
// ---------------------------------------------------------------------------
__global__ __launch_bounds__(256) void gemm_count(const float* __restrict__ h,
                                                  const float* __restrict__ W,
                                                  const float* __restrict__ a,
                                                  const int* __restrict__ ei,
                                                  unsigned* __restrict__ WhB,
                                                  float* __restrict__ s1,
                                                  float* __restrict__ s2,
                                                  int* __restrict__ count,
                                                  int* __restrict__ rank) {
    __shared__ float hs[64][128];
    const int tid = threadIdx.x;

    if (blockIdx.x >= GEMM_BLOCKS) {
        // ---- histogram + rank part ----
        const int base = (blockIdx.x - GEMM_BLOCKS) * 256 + tid;
        const int stride = CNT_BLOCKS * 256;
        int idx[EPT], r[EPT];
        #pragma unroll
        for (int k = 0; k < EPT; ++k) {
            idx[k] = base + k * stride;
            r[k] = (idx[k] < NEDGES) ? ei[idx[k]] : -1;
        }
        int rk[EPT];
        #pragma unroll
        for (int k = 0; k < EPT; ++k)
            if (r[k] >= 0) rk[k] = atomicAdd(&count[r[k]], 1);
        #pragma unroll
        for (int k = 0; k < EPT; ++k)
            if (r[k] >= 0) rank[idx[k]] = rk[k];
        return;
    }

    // ---- GEMM part ----
    const int row0 = blockIdx.x * 64;

    #pragma unroll
    for (int i = 0; i < 32; ++i) {
        int idx = tid + i * 256;
        int r = idx >> 7, c = idx & 127;
        int gr = row0 + r;
        hs[r][c] = (gr < NNODES) ? h[gr * NF + c] : 0.f;
    }
    __syncthreads();

    const int c2 = (tid & 63) * 2;      // this lane's 2 output columns
    const int rg = (tid >> 6) * 16;     // wave's first row (16 rows per wave)

    float2 acc[16];
    #pragma unroll
    for (int r = 0; r < 16; ++r) acc[r] = make_float2(0.f, 0.f);

    // W double-buffer: wq = current 4 k-substeps, wn = next
    float2 wq[4], wn[4];
    #pragma unroll
    for (int kk = 0; kk < 4; ++kk)
        wq[kk] = *(const float2*)&W[kk * NF + c2];

    for (int k = 0; k < 128; k += 4) {
        const int kn = (k + 4 < 128) ? (k + 4) : 0;   // last iter: dummy reload
        #pragma unroll
        for (int kk = 0; kk < 4; ++kk)
            wn[kk] = *(const float2*)&W[(kn + kk) * NF + c2];
        #pragma unroll
        for (int r = 0; r < 16; ++r) {
            float4 hv = *(const float4*)&hs[rg + r][k];   // wave-uniform broadcast
            acc[r].x += hv.x * wq[0].x + hv.y * wq[1].x + hv.z * wq[2].x + hv.w * wq[3].x;
            acc[r].y += hv.x * wq[0].y + hv.y * wq[1].y + hv.z * wq[2].y + hv.w * wq[3].y;
        }
        #pragma unroll
        for (int kk = 0; kk < 4; ++kk) wq[kk] = wn[kk];
    }

    // store Wh as bf16 (RNE): row = 64 dwords; lane owns dword (tid&63)
    #pragma unroll
    for (int r = 0; r < 16; ++r) {
        int gr = row0 + rg + r;
        if (gr < NNODES)
            WhB[(size_t)gr * 64 + (tid & 63)] = pack2bf(acc[r].x, acc[r].y);
    }

    // fused s1/s2 (f32, full-wave reduction over 128 cols)
    float2 a1v = *(const float2*)&a[c2];
    float2 a2v = *(const float2*)&a[128 + c2];
    #pragma unroll
    for (int r = 0; r < 16; ++r) {
        float p1 = acc[r].x * a1v.x + acc[r].y * a1v.y;
        float p2 = acc[r].x * a2v.x + acc[r].y * a2v.y;
        #pragma unroll
        for (int off = 32; off; off >>= 1) {
            p1 += __shfl_xor(p1, off);
            p2 += __shfl_xor(p2, off);
        }
        int gr = row0 + rg + r;
        if ((tid & 63) == 0 && gr < NNODES) { s1[gr] = p1; s2[gr] = p2; }
    }
}

// ---------------------------------------------------------------------------
// K3a: per-chunk sums
// ---------------------------------------------------------------------------
__global__ __launch_bounds__(256) void chunk_sums(const int* __restrict__ count,
                                                  int* __restrict__ chunkSum) {
    __shared__ int red[256];
    int t = threadIdx.x;
    int idx = blockIdx.x * 256 + t;
    red[t] = (idx < NNODES) ? count[idx] : 0;
    __syncthreads();
    #pragma unroll
    for (int off = 128; off; off >>= 1) {
        if (t < off) red[t] += red[t + off];
        __syncthreads();
    }
    if (t == 0) chunkSum[blockIdx.x] = red[0];
}

// ---------------------------------------------------------------------------
// K3b: scan chunk sums (single 256-thread block)
// ---------------------------------------------------------------------------
__global__ __launch_bounds__(256) void scan_chunks(const int* __restrict__ chunkSum,
                                                   int* __restrict__ chunkBase,
                                                   int* __restrict__ rowstart) {
    __shared__ int s[256];
    int t = threadIdx.x;
    int v = (t < NBLK) ? chunkSum[t] : 0;
    s[t] = v;
    __syncthreads();
    #pragma unroll
    for (int off = 1; off < 256; off <<= 1) {
        int x = (t >= off) ? s[t - off] : 0;
        __syncthreads();
        s[t] += x;
        __syncthreads();
    }
    if (t < NBLK) chunkBase[t] = s[t] - v;
    if (t == 255) rowstart[NNODES] = s[255];
}

// ---------------------------------------------------------------------------
// K3c: local scan + chunk base -> rowstart
// ---------------------------------------------------------------------------
__global__ __launch_bounds__(256) void write_rowstart(const int* __restrict__ count,
                                                      const int* __restrict__ chunkBase,
                                                      int* __restrict__ rowstart) {
    __shared__ int s[256];
    int t = threadIdx.x;
    int idx = blockIdx.x * 256 + t;
    int v = (idx < NNODES) ? count[idx] : 0;
    s[t] = v;
    __syncthreads();
    #pragma unroll
    for (int off = 1; off < 256; off <<= 1) {
        int x = (t >= off) ? s[t - off] : 0;
        __syncthreads();
        s[t] += x;
        __syncthreads();
    }
    if (idx < NNODES) rowstart[idx] = chunkBase[blockIdx.x] + s[t] - v;
}

// ---------------------------------------------------------------------------
// K4: scatter pass — NO atomics: pos = rowstart[r] + rank[i]
//     pair[pos] = (leaky_relu(s1[r]+s2[c]), col)      [RAW e — exp happens later
//     against the row-sum shift, replicating reference EPS/underflow semantics]
// ---------------------------------------------------------------------------
__global__ __launch_bounds__(256) void scatter_edges(const int* __restrict__ ei,
                                                     const int* __restrict__ rank,
                                                     const int* __restrict__ rowstart,
                                                     const float* __restrict__ s1,
                                                     const float* __restrict__ s2,
                                                     float2* __restrict__ pair) {
    const int base = blockIdx.x * blockDim.x + threadIdx.x;
    const int stride = gridDim.x * blockDim.x;
    int idx[EPT], r[EPT], c[EPT], rk[EPT];
    #pragma unroll
    for (int k = 0; k < EPT; ++k) {
        idx[k] = base + k * stride;
        if (idx[k] < NEDGES) {
            r[k] = ei[idx[k]];
            c[k] = ei[NEDGES + idx[k]];
            rk[k] = rank[idx[k]];
        } else r[k] = -1;
    }
    float sv1[EPT], sv2[EPT];
    int rs[EPT];
    #pragma unroll
    for (int k = 0; k < EPT; ++k)
        if (r[k] >= 0) { sv1[k] = s1[r[k]]; sv2[k] = s2[c[k]]; rs[k] = rowstart[r[k]]; }
    #pragma unroll
    for (int k = 0; k < EPT; ++k)
        if (r[k] >= 0) {
            float s = sv1[k] + sv2[k];
            float ev = (s >= 0.f) ? s : ALPHA * s;
            pair[rs[k] + rk[k]] = make_float2(ev, __int_as_float(c[k]));
        }
}

// ---------------------------------------------------------------------------
// K5: per-row aggregation, one wave per row.
//   pass A1: rs = sum(e)                       (reference's rowsum shift)
//   pass A2: w_j = exp(e_j - rs) cached in LDS (deg<=128), dsum = sum(w)
//   pass B : acc += (w/(dsum+EPS)) * WhB[col]  (pure gather+FMA, x8 ILP)
//   deg>128 fallback: recompute exp in pass B (exact same arithmetic).
// ---------------------------------------------------------------------------
__global__ __launch_bounds__(256) void aggregate(const int* __restrict__ rowstart,
                                                 const float2* __restrict__ pair,
                                                 const unsigned* __restrict__ WhB,
                                                 float* __restrict__ out) {
    __shared__ float wsh[4][MAXDEG];
    const int wid = threadIdx.x >> 6;
    const int lane = threadIdx.x & 63;
    const int row = blockIdx.x * 4 + wid;
    if (row >= NNODES) return;
    const int start = rowstart[row];
    const int end = rowstart[row + 1];
    const int deg = end - start;

    // pass A1: row-sum of e (replicates reference rowsum)
    float esum = 0.f;
    for (int j = start + lane; j < end; j += 64) esum += pair[j].x;
    #pragma unroll
    for (int off = 32; off; off >>= 1) esum += __shfl_xor(esum, off);
    const float rs = esum;

    // pass A2: exp(e - rs), cache in LDS if it fits, accumulate denom
    float dsum = 0.f;
    const bool fits = (deg <= MAXDEG);
    if (fits) {
        for (int j = start + lane; j < end; j += 64) {
            float x = expf(pair[j].x - rs);
            wsh[wid][j - start] = x;
            dsum += x;
        }
    } else {
        for (int j = start + lane; j < end; j += 64) dsum += expf(pair[j].x - rs);
    }
    #pragma unroll
    for (int off = 32; off; off >>= 1) dsum += __shfl_xor(dsum, off);
    const float invd = 1.0f / (dsum + EPS);

    // pass B: weighted gather-accumulate, 8 gathers in flight
    float accx = 0.f, accy = 0.f;
    if (fits) {
        int j = start;
        for (; j + 8 <= end; j += 8) {
            int cs[8];
            #pragma unroll
            for (int k = 0; k < 8; ++k) cs[k] = __float_as_int(pair[j + k].y);
            unsigned u[8];
            #pragma unroll
            for (int k = 0; k < 8; ++k) u[k] = WhB[(size_t)cs[k] * 64 + lane];
            #pragma unroll
            for (int k = 0; k < 8; ++k) {
                float w = wsh[wid][j - start + k] * invd;
                accx += w * __uint_as_float(u[k] << 16);
                accy += w * __uint_as_float(u[k] & 0xFFFF0000u);
            }
        }
        for (; j < end; ++j) {
            int c = __float_as_int(pair[j].y);
            unsigned u = WhB[(size_t)c * 64 + lane];
            float w = wsh[wid][j - start] * invd;
            accx += w * __uint_as_float(u << 16);
            accy += w * __uint_as_float(u & 0xFFFF0000u);
        }
    } else {
        for (int j = start; j < end; ++j) {
            float2 p = pair[j];
            unsigned u = WhB[(size_t)__float_as_int(p.y) * 64 + lane];
            float w = expf(p.x - rs) * invd;
            accx += w * __uint_as_float(u << 16);
            accy += w * __uint_as_float(u & 0xFFFF0000u);
        }
    }
    // lane owns columns 2*lane, 2*lane+1
    ((float2*)out)[(size_t)row * 64 + lane] = make_float2(accx, accy);
}

// ---------------------------------------------------------------------------
extern "C" void kernel_launch(void* const* d_in, const int* in_sizes, int n_in,
                              void* d_out, int out_size, void* d_ws, size_t ws_size,
                              hipStream_t stream) {
    const float* h  = (const float*)d_in[0];
    const int*   ei = (const int*)d_in[1];
    const float* W  = (const float*)d_in[2];
    const float* a  = (const float*)d_in[3];
    float* out = (float*)d_out;

    char* ws = (char*)d_ws;
    size_t off = 0;
    auto alloc = [&](size_t bytes) -> void* {
        void* p = ws + off;
        off += (bytes + 255) & ~(size_t)255;
        return p;
    };

    unsigned* WhB      = (unsigned*)alloc((size_t)NNODES * 64 * 4);  // bf16 Wh, 64 dwords/row
    int*      count    = (int*)alloc((size_t)NNODES * 4);
    float*    s1       = (float*)alloc((size_t)NNODES * 4);
    float*    s2       = (float*)alloc((size_t)NNODES * 4);
    int*      rowstart = (int*)alloc((size_t)(NNODES + 1) * 4);
    int*      rank     = (int*)alloc((size_t)NEDGES * 4);
    float2*   pair     = (float2*)alloc((size_t)NEDGES * 8);
    int*      chunkSum = (int*)alloc((size_t)NBLK * 4);
    int*      chunkBase= (int*)alloc((size_t)NBLK * 4);

    hipMemsetAsync(count, 0, (size_t)NNODES * 4, stream);

    // K1: fused GEMM(bf16 out)+s1/s2  ||  histogram+rank
    gemm_count<<<GEMM_BLOCKS + CNT_BLOCKS, 256, 0, stream>>>(h, W, a, ei, WhB, s1, s2, count, rank);
    // K3: hierarchical scan
    chunk_sums<<<NBLK, 256, 0, stream>>>(count, chunkSum);
    scan_chunks<<<1, 256, 0, stream>>>(chunkSum, chunkBase, rowstart);
    write_rowstart<<<NBLK, 256, 0, stream>>>(count, chunkBase, rowstart);
    // K4: atomic-free scatter, stores raw e
    scatter_edges<<<CNT_BLOCKS, 256, 0, stream>>>(ei, rank, rowstart, s1, s2, pair);
    // K5: aggregate (exp vs row-sum shift, LDS-cached weights, bf16 gather)
    aggregate<<<(NNODES + 3) / 4, 256, 0, stream>>>(rowstart, pair, WhB, out);
}

// Round 8
// 135.077 us; speedup vs baseline: 1.1086x; 1.1086x over previous
//
#include <hip/hip_runtime.h>
#include <hip/hip_bf16.h>
#include <math.h>

#define NNODES 50000
#define NF 128
#define NEDGES 800000
#define ALPHA 0.2f
#define EPS 1e-16f
#define NBLK 196            // ceil(50000/256) chunks for the hierarchical scan
#define EPT 8               // edges per thread in edge passes
#define GEMM_BLOCKS 782     // ceil(50000/64)
#define CNT_BLOCKS 391      // ceil(800000/(8*256))
#define MAXDEG 128          // LDS weight-cache fast path limit

typedef __attribute__((ext_vector_type(8))) short bf16x8;
typedef __attribute__((ext_vector_type(4))) float f32x4;

// bf16 RNE helpers
__device__ inline unsigned bf16rne(float x) {
    unsigned u = __float_as_uint(x);
    return (u + 0x7FFFu + ((u >> 16) & 1u)) >> 16;
}

// ---------------------------------------------------------------------------
// K0: prep. blocks 0-7: WbF = fragment-ordered bf16 W (B-operand layout for
//     mfma_f32_16x16x32_bf16: slot s=(ks*8+ct)*64+lane holds 8 bf16, elem j =
//     W[k][c], k=ks*32+16*(j>>2)+(lane>>4)*4+(j&3), c=ct*16+(lane&15)).
//     block 8: Wa1 = W@a1, Wa2 = W@a2 (f32 exact path for s1/s2).
// ---------------------------------------------------------------------------
__global__ __launch_bounds__(256) void prep(const float* __restrict__ W,
                                            const float* __restrict__ a,
                                            ushort* __restrict__ WbF,
                                            float* __restrict__ Wa1,
                                            float* __restrict__ Wa2) {
    if (blockIdx.x < 8) {
        int s = blockIdx.x * 256 + threadIdx.x;   // slot 0..2047
        int l = s & 63;
        int ct = (s >> 6) & 7;
        int ks = s >> 9;                          // 0..3
        int c = ct * 16 + (l & 15);
        int g = l >> 4;
        ushort v[8];
        #pragma unroll
        for (int j = 0; j < 8; ++j) {
            int k = ks * 32 + ((j >> 2) << 4) + g * 4 + (j & 3);
            v[j] = (ushort)bf16rne(W[k * NF + c]);
        }
        *(uint4*)&WbF[(size_t)s * 8] = *(uint4*)v;
    } else {
        int k = threadIdx.x;
        if (k < NF) {
            float t1 = 0.f, t2 = 0.f;
            for (int c = 0; c < NF; ++c) {
                float w = W[k * NF + c];
                t1 += w * a[c];
                t2 += w * a[NF + c];
            }
            Wa1[k] = t1;
            Wa2[k] = t2;
        }
    }
}

// ---------------------------------------------------------------------------
// K1: MFMA bf16 GEMM. 64 rows x 128 cols per block (4 waves; wave = 16 rows).
// A: per-lane f32 loads from h (row = lane&15 of the wave strip), cvt->bf16.
// B: WbF copied verbatim to LDS; frag = lane-contiguous ds_read_b128.
// Fused: s1/s2 in f32 via h . Wa1/Wa2 on the same loaded values (exact path).
// Wh stored bf16 (RNE) as before.
// ---------------------------------------------------------------------------
__global__ __launch_bounds__(256) void gemm_mfma(const float* __restrict__ h,
                                                 const ushort* __restrict__ WbF,
                                                 const float* __restrict__ Wa1,
                                                 const float* __restrict__ Wa2,
                                                 ushort* __restrict__ WhBu,
                                                 float* __restrict__ s1,
                                                 float* __restrict__ s2) {
    __shared__ ushort ldsB[16384];   // 32 KB
    const int tid = threadIdx.x;

    // stage WbF -> LDS verbatim (32 KB)
    #pragma unroll
    for (int i = 0; i < 8; ++i) {
        int off8 = (tid + i * 256) * 8;
        *(uint4*)&ldsB[off8] = *(const uint4*)&WbF[off8];
    }
    __syncthreads();

    const int lane = tid & 63;
    const int wrow = tid >> 6;          // wave's 16-row strip
    const int m = lane & 15;            // A row within strip
    const int g = lane >> 4;            // 0..3 (k-group)
    const int row = blockIdx.x * 64 + wrow * 16 + m;
    const int rowc = (row < NNODES) ? row : 0;

    f32x4 acc[8];
    #pragma unroll
    for (int t = 0; t < 8; ++t) acc[t] = (f32x4){0.f, 0.f, 0.f, 0.f};

    float p1 = 0.f, p2 = 0.f;
    #pragma unroll
    for (int ks = 0; ks < 4; ++ks) {
        const float4 ha = *(const float4*)&h[(size_t)rowc * NF + ks * 32 + g * 4];
        const float4 hb = *(const float4*)&h[(size_t)rowc * NF + ks * 32 + 16 + g * 4];
        // f32 s1/s2 partials (exact path; same elements as the A-frag)
        const float4 wa1a = *(const float4*)&Wa1[ks * 32 + g * 4];
        const float4 wa1b = *(const float4*)&Wa1[ks * 32 + 16 + g * 4];
        const float4 wa2a = *(const float4*)&Wa2[ks * 32 + g * 4];
        const float4 wa2b = *(const float4*)&Wa2[ks * 32 + 16 + g * 4];
        p1 += ha.x * wa1a.x + ha.y * wa1a.y + ha.z * wa1a.z + ha.w * wa1a.w
            + hb.x * wa1b.x + hb.y * wa1b.y + hb.z * wa1b.z + hb.w * wa1b.w;
        p2 += ha.x * wa2a.x + ha.y * wa2a.y + ha.z * wa2a.z + ha.w * wa2a.w
            + hb.x * wa2b.x + hb.y * wa2b.y + hb.z * wa2b.z + hb.w * wa2b.w;
        // pack A fragment (elems 0-3: k=ks*32+g*4+j; 4-7: +16)
        bf16x8 afrag;
        afrag[0] = (short)bf16rne(ha.x);
        afrag[1] = (short)bf16rne(ha.y);
        afrag[2] = (short)bf16rne(ha.z);
        afrag[3] = (short)bf16rne(ha.w);
        afrag[4] = (short)bf16rne(hb.x);
        afrag[5] = (short)bf16rne(hb.y);
        afrag[6] = (short)bf16rne(hb.z);
        afrag[7] = (short)bf16rne(hb.w);
        #pragma unroll
        for (int ct = 0; ct < 8; ++ct) {
            bf16x8 bfrag = *(bf16x8*)&ldsB[((ks * 8 + ct) * 64 + lane) * 8];
            acc[ct] = __builtin_amdgcn_mfma_f32_16x16x32_bf16(afrag, bfrag, acc[ct], 0, 0, 0);
        }
    }

    // s1/s2: reduce partials over the 4 k-groups (lanes m, m+16, m+32, m+48)
    p1 += __shfl_xor(p1, 16); p1 += __shfl_xor(p1, 32);
    p2 += __shfl_xor(p2, 16); p2 += __shfl_xor(p2, 32);
    if (g == 0 && row < NNODES) { s1[row] = p1; s2[row] = p2; }

    // C store: lane, reg r -> row = strip + (lane>>4)*4 + r, col = ct*16 + (lane&15)
    const int orow = blockIdx.x * 64 + wrow * 16 + g * 4;
    #pragma unroll
    for (int r = 0; r < 4; ++r) {
        int gr = orow + r;
        if (gr < NNODES) {
            #pragma unroll
            for (int ct = 0; ct < 8; ++ct)
                WhBu[(size_t)gr * NF + ct * 16 + m] = (ushort)bf16rne(acc[ct][r]);
        }
    }
}

// ---------------------------------------------------------------------------
// K2: degree histogram + per-edge rank (8 independent atomic chains/thread)
// ---------------------------------------------------------------------------
__global__ __launch_bounds__(256) void count_rank(const int* __restrict__ ei,
                                                  int* __restrict__ count,
                                                  int* __restrict__ rank) {
    const int base = blockIdx.x * blockDim.x + threadIdx.x;
    const int stride = gridDim.x * blockDim.x;
    int idx[EPT], r[EPT];
    #pragma unroll
    for (int k = 0; k < EPT; ++k) {
        idx[k] = base + k * stride;
        r[k] = (idx[k] < NEDGES) ? ei[idx[k]] : -1;
    }
    int rk[EPT];
    #pragma unroll
    for (int k = 0; k < EPT; ++k)
        if (r[k] >= 0) rk[k] = atomicAdd(&count[r[k]], 1);
    #pragma unroll
    for (int k = 0; k < EPT; ++k)
        if (r[k] >= 0) rank[idx[k]] = rk[k];
}

// ---------------------------------------------------------------------------
// K3a: per-chunk sums
// ---------------------------------------------------------------------------
__global__ __launch_bounds__(256) void chunk_sums(const int* __restrict__ count,
                                                  int* __restrict__ chunkSum) {
    __shared__ int red[256];
    int t = threadIdx.x;
    int idx = blockIdx.x * 256 + t;
    red[t] = (idx < NNODES) ? count[idx] : 0;
    __syncthreads();
    #pragma unroll
    for (int off = 128; off; off >>= 1) {
        if (t < off) red[t] += red[t + off];
        __syncthreads();
    }
    if (t == 0) chunkSum[blockIdx.x] = red[0];
}

// ---------------------------------------------------------------------------
// K3b: scan chunk sums (single 256-thread block)
// ---------------------------------------------------------------------------
__global__ __launch_bounds__(256) void scan_chunks(const int* __restrict__ chunkSum,
                                                   int* __restrict__ chunkBase,
                                                   int* __restrict__ rowstart) {
    __shared__ int s[256];
    int t = threadIdx.x;
    int v = (t < NBLK) ? chunkSum[t] : 0;
    s[t] = v;
    __syncthreads();
    #pragma unroll
    for (int off = 1; off < 256; off <<= 1) {
        int x = (t >= off) ? s[t - off] : 0;
        __syncthreads();
        s[t] += x;
        __syncthreads();
    }
    if (t < NBLK) chunkBase[t] = s[t] - v;
    if (t == 255) rowstart[NNODES] = s[255];
}

// ---------------------------------------------------------------------------
// K3c: local scan + chunk base -> rowstart
// ---------------------------------------------------------------------------
__global__ __launch_bounds__(256) void write_rowstart(const int* __restrict__ count,
                                                      const int* __restrict__ chunkBase,
                                                      int* __restrict__ rowstart) {
    __shared__ int s[256];
    int t = threadIdx.x;
    int idx = blockIdx.x * 256 + t;
    int v = (idx < NNODES) ? count[idx] : 0;
    s[t] = v;
    __syncthreads();
    #pragma unroll
    for (int off = 1; off < 256; off <<= 1) {
        int x = (t >= off) ? s[t - off] : 0;
        __syncthreads();
        s[t] += x;
        __syncthreads();
    }
    if (idx < NNODES) rowstart[idx] = chunkBase[blockIdx.x] + s[t] - v;
}

// ---------------------------------------------------------------------------
// K4: scatter pass — NO atomics: pos = rowstart[r] + rank[i]
//     pair[pos] = (leaky_relu(s1[r]+s2[c]), col)  [raw e; exp happens in K5
//     against the row-sum shift, replicating reference EPS/underflow semantics]
// ---------------------------------------------------------------------------
__global__ __launch_bounds__(256) void scatter_edges(const int* __restrict__ ei,
                                                     const int* __restrict__ rank,
                                                     const int* __restrict__ rowstart,
                                                     const float* __restrict__ s1,
                                                     const float* __restrict__ s2,
                                                     float2* __restrict__ pair) {
    const int base = blockIdx.x * blockDim.x + threadIdx.x;
    const int stride = gridDim.x * blockDim.x;
    int idx[EPT], r[EPT], c[EPT], rk[EPT];
    #pragma unroll
    for (int k = 0; k < EPT; ++k) {
        idx[k] = base + k * stride;
        if (idx[k] < NEDGES) {
            r[k] = ei[idx[k]];
            c[k] = ei[NEDGES + idx[k]];
            rk[k] = rank[idx[k]];
        } else r[k] = -1;
    }
    float sv1[EPT], sv2[EPT];
    int rs[EPT];
    #pragma unroll
    for (int k = 0; k < EPT; ++k)
        if (r[k] >= 0) { sv1[k] = s1[r[k]]; sv2[k] = s2[c[k]]; rs[k] = rowstart[r[k]]; }
    #pragma unroll
    for (int k = 0; k < EPT; ++k)
        if (r[k] >= 0) {
            float s = sv1[k] + sv2[k];
            float ev = (s >= 0.f) ? s : ALPHA * s;
            pair[rs[k] + rk[k]] = make_float2(ev, __int_as_float(c[k]));
        }
}

// ---------------------------------------------------------------------------
// K5: per-row aggregation, one wave per row.
//   pass A1: rs = sum(e)                       (reference's rowsum shift)
//   pass A2: w_j = exp(e_j - rs) cached in LDS (deg<=128), dsum = sum(w)
//   pass B : acc += (w/(dsum+EPS)) * WhB[col]  (pure gather+FMA, x8 ILP)
// ---------------------------------------------------------------------------
__global__ __launch_bounds__(256) void aggregate(const int* __restrict__ rowstart,
                                                 const float2* __restrict__ pair,
                                                 const unsigned* __restrict__ WhB,
                                                 float* __restrict__ out) {
    __shared__ float wsh[4][MAXDEG];
    const int wid = threadIdx.x >> 6;
    const int lane = threadIdx.x & 63;
    const int row = blockIdx.x * 4 + wid;
    if (row >= NNODES) return;
    const int start = rowstart[row];
    const int end = rowstart[row + 1];
    const int deg = end - start;

    // pass A1: row-sum of e
    float esum = 0.f;
    for (int j = start + lane; j < end; j += 64) esum += pair[j].x;
    #pragma unroll
    for (int off = 32; off; off >>= 1) esum += __shfl_xor(esum, off);
    const float rs = esum;

    // pass A2: exp(e - rs), cache in LDS if it fits, accumulate denom
    float dsum = 0.f;
    const bool fits = (deg <= MAXDEG);
    if (fits) {
        for (int j = start + lane; j < end; j += 64) {
            float x = expf(pair[j].x - rs);
            wsh[wid][j - start] = x;
            dsum += x;
        }
    } else {
        for (int j = start + lane; j < end; j += 64) dsum += expf(pair[j].x - rs);
    }
    #pragma unroll
    for (int off = 32; off; off >>= 1) dsum += __shfl_xor(dsum, off);
    const float invd = 1.0f / (dsum + EPS);

    // pass B: weighted gather-accumulate, 8 gathers in flight
    float accx = 0.f, accy = 0.f;
    if (fits) {
        int j = start;
        for (; j + 8 <= end; j += 8) {
            int cs[8];
            #pragma unroll
            for (int k = 0; k < 8; ++k) cs[k] = __float_as_int(pair[j + k].y);
            unsigned u[8];
            #pragma unroll
            for (int k = 0; k < 8; ++k) u[k] = WhB[(size_t)cs[k] * 64 + lane];
            #pragma unroll
            for (int k = 0; k < 8; ++k) {
                float w = wsh[wid][j - start + k] * invd;
                accx += w * __uint_as_float(u[k] << 16);
                accy += w * __uint_as_float(u[k] & 0xFFFF0000u);
            }
        }
        for (; j < end; ++j) {
            int c = __float_as_int(pair[j].y);
            unsigned u = WhB[(size_t)c * 64 + lane];
            float w = wsh[wid][j - start] * invd;
            accx += w * __uint_as_float(u << 16);
            accy += w * __uint_as_float(u & 0xFFFF0000u);
        }
    } else {
        for (int j = start; j < end; ++j) {
            float2 p = pair[j];
            unsigned u = WhB[(size_t)__float_as_int(p.y) * 64 + lane];
            float w = expf(p.x - rs) * invd;
            accx += w * __uint_as_float(u << 16);
            accy += w * __uint_as_float(u & 0xFFFF0000u);
        }
    }
    ((float2*)out)[(size_t)row * 64 + lane] = make_float2(accx, accy);
}

// ---------------------------------------------------------------------------
extern "C" void kernel_launch(void* const* d_in, const int* in_sizes, int n_in,
                              void* d_out, int out_size, void* d_ws, size_t ws_size,
                              hipStream_t stream) {
    const float* h  = (const float*)d_in[0];
    const int*   ei = (const int*)d_in[1];
    const float* W  = (const float*)d_in[2];
    const float* a  = (const float*)d_in[3];
    float* out = (float*)d_out;

    char* ws = (char*)d_ws;
    size_t off = 0;
    auto alloc = [&](size_t bytes) -> void* {
        void* p = ws + off;
        off += (bytes + 255) & ~(size_t)255;
        return p;
    };

    unsigned* WhB      = (unsigned*)alloc((size_t)NNODES * 64 * 4);  // bf16 Wh table
    ushort*   WbF      = (ushort*)alloc((size_t)2048 * 16);          // frag-ordered bf16 W
    float*    Wa1      = (float*)alloc((size_t)NF * 4);
    float*    Wa2      = (float*)alloc((size_t)NF * 4);
    int*      count    = (int*)alloc((size_t)NNODES * 4);
    float*    s1       = (float*)alloc((size_t)NNODES * 4);
    float*    s2       = (float*)alloc((size_t)NNODES * 4);
    int*      rowstart = (int*)alloc((size_t)(NNODES + 1) * 4);
    int*      rank     = (int*)alloc((size_t)NEDGES * 4);
    float2*   pair     = (float2*)alloc((size_t)NEDGES * 8);
    int*      chunkSum = (int*)alloc((size_t)NBLK * 4);
    int*      chunkBase= (int*)alloc((size_t)NBLK * 4);

    hipMemsetAsync(count, 0, (size_t)NNODES * 4, stream);

    // K0: prep (WbF frag table + Wa1/Wa2)
    prep<<<9, 256, 0, stream>>>(W, a, WbF, Wa1, Wa2);
    // K1: MFMA bf16 GEMM + fused f32 s1/s2
    gemm_mfma<<<GEMM_BLOCKS, 256, 0, stream>>>(h, WbF, Wa1, Wa2, (ushort*)WhB, s1, s2);
    // K2: histogram + rank
    count_rank<<<CNT_BLOCKS, 256, 0, stream>>>(ei, count, rank);
    // K3: hierarchical scan
    chunk_sums<<<NBLK, 256, 0, stream>>>(count, chunkSum);
    scan_chunks<<<1, 256, 0, stream>>>(chunkSum, chunkBase, rowstart);
    write_rowstart<<<NBLK, 256, 0, stream>>>(count, chunkBase, rowstart);
    // K4: atomic-free scatter, stores raw e
    scatter_edges<<<CNT_BLOCKS, 256, 0, stream>>>(ei, rank, rowstart, s1, s2, pair);
    // K5: aggregate
    aggregate<<<(NNODES + 3) / 4, 256, 0, stream>>>(rowstart, pair, WhB, out);
}